// Round 1
// baseline (497.871 us; speedup 1.0000x reference)
//
#include <hip/hip_runtime.h>
#include <math.h>

#define NN 20000
#define NE 320000
#define NF (NN*64)
#define TB 16

__device__ __forceinline__ float silu_f(float x){ return x / (1.0f + expf(-x)); }

// Transpose the per-species residual weight matrices so the node-post kernel
// can read them column-coalesced. 10 species x 64 x 64 = 40960 elements each.
__global__ __launch_bounds__(256) void k_transpose_res(
    const float* __restrict__ Ws, const float* __restrict__ Wv,
    float* __restrict__ Wst, float* __restrict__ Wvt)
{
  int i = blockIdx.x*256 + threadIdx.x;   // 0..40959, exact
  int spec = i >> 12;
  int g = (i >> 6) & 63;
  int f = i & 63;
  Wst[spec*4096 + f*64 + g] = Ws[i];
  Wvt[spec*4096 + f*64 + g] = Wv[i];
}

// h_s = (s @ W_in_s)/8 ; h_v[c] = (v_c @ W_in_v)/8.  One wave per node, lane=g.
__global__ __launch_bounds__(256) void k_node_pre(
    const float* __restrict__ node_feats, const float* __restrict__ W_in_s,
    const float* __restrict__ W_in_v, float* __restrict__ h_s, float* __restrict__ h_v)
{
  __shared__ float sh[4][4][64];
  int wave = threadIdx.x >> 6, lane = threadIdx.x & 63;
  int n = blockIdx.x*4 + wave;
  int o = n*64 + lane;
  float4 nf = *(const float4*)(node_feats + (size_t)o*4);
  sh[wave][0][lane]=nf.x; sh[wave][1][lane]=nf.y; sh[wave][2][lane]=nf.z; sh[wave][3][lane]=nf.w;
  __syncthreads();
  float as=0.f, av0=0.f, av1=0.f, av2=0.f;
  #pragma unroll 8
  for(int f=0; f<64; ++f){
    float ws = W_in_s[f*64+lane], wv = W_in_v[f*64+lane];
    as  += sh[wave][0][f]*ws;
    av0 += sh[wave][1][f]*wv;
    av1 += sh[wave][2][f]*wv;
    av2 += sh[wave][3][f]*wv;
  }
  h_s[o]      = as *0.125f;
  h_v[o]      = av0*0.125f;
  h_v[NF+o]   = av1*0.125f;
  h_v[2*NF+o] = av2*0.125f;
}

// Edge kernel: one wave handles TB=16 edges, lane = feature.
__global__ __launch_bounds__(256) void k_edge(
    const float* __restrict__ vectors, const float* __restrict__ radial,
    const int* __restrict__ senders, const int* __restrict__ receivers,
    const float* __restrict__ mlp_w1, const float* __restrict__ mlp_w2,
    const float* __restrict__ h_s, const float* __restrict__ h_v,
    float* __restrict__ agg_s, float* __restrict__ agg_v)
{
  __shared__ float rad[4][128];       // TB*8 radial values per wave
  __shared__ float hid[4][TB][64];
  int wave = threadIdx.x >> 6, lane = threadIdx.x & 63;
  int wgid = blockIdx.x*4 + wave;     // 0..19999
  int e0 = wgid*TB;
  // stage radial rows (contiguous 128 floats per wave)
  rad[wave][lane]    = radial[e0*8 + lane];
  rad[wave][64+lane] = radial[e0*8 + 64 + lane];
  __syncthreads();
  // hidden = silu(rad @ w1): lane = hidden unit
  #pragma unroll
  for(int t=0;t<TB;++t){
    float acc=0.f;
    #pragma unroll
    for(int r=0;r<8;++r) acc += rad[wave][t*8+r]*mlp_w1[r*64+lane];
    hid[wave][t][lane] = silu_f(acc);
  }
  __syncthreads();
  // w[j][t][lane] = hidden[t] @ w2[:, j*64+lane]
  float w[5][TB];
  #pragma unroll
  for(int j=0;j<5;++j)
    #pragma unroll
    for(int t=0;t<TB;++t) w[j][t]=0.f;
  for(int h=0; h<64; h+=2){
    float b0[5], b1[5];
    #pragma unroll
    for(int j=0;j<5;++j){
      b0[j]=mlp_w2[h*320     + j*64 + lane];
      b1[j]=mlp_w2[(h+1)*320 + j*64 + lane];
    }
    #pragma unroll
    for(int t=0;t<TB;++t){
      float2 hb = *(const float2*)&hid[wave][t][h];
      #pragma unroll
      for(int j=0;j<5;++j) w[j][t] = fmaf(hb.x, b0[j], fmaf(hb.y, b1[j], w[j][t]));
    }
  }
  // per-edge message build + scatter
  #pragma unroll
  for(int t=0;t<TB;++t){
    int e = e0 + t;
    int snd = senders[e], rcv = receivers[e];
    float vx=vectors[e*3], vy=vectors[e*3+1], vz=vectors[e*3+2];
    float rinv = 1.0f/sqrtf(vx*vx+vy*vy+vz*vz+1e-12f);
    float y0=vx*rinv, y1=vy*rinv, y2=vz*rinv;
    int so = snd*64+lane, ro = rcv*64+lane;
    float ss  = h_s[so];
    float sv0 = h_v[so], sv1 = h_v[NF+so], sv2 = h_v[2*NF+so];
    float dot = sv0*y0 + sv1*y1 + sv2*y2;
    float ms  = w[0][t]*ss + w[1][t]*dot;
    float w2s = w[2][t]*ss, w3t = w[3][t], w4t = w[4][t];
    float mv0 = w2s*y0 + w3t*sv0 + w4t*(sv1*y2 - sv2*y1);
    float mv1 = w2s*y1 + w3t*sv1 + w4t*(sv2*y0 - sv0*y2);
    float mv2 = w2s*y2 + w3t*sv2 + w4t*(sv0*y1 - sv1*y0);
    atomicAdd(&agg_s[ro],      ms);
    atomicAdd(&agg_v[ro],      mv0);
    atomicAdd(&agg_v[NF+ro],   mv1);
    atomicAdd(&agg_v[2*NF+ro], mv2);
  }
}

// Node post-pass: out linears, species polynomials, residual, readout.
__global__ __launch_bounds__(256) void k_node_post(
  const float* __restrict__ node_feats, const int* __restrict__ specie,
  const float* __restrict__ agg_s, const float* __restrict__ agg_v,
  const float* __restrict__ Wrst, const float* __restrict__ Wrvt,
  const float* __restrict__ W_out_s, const float* __restrict__ W_out_v,
  const float* __restrict__ W_prod_s, const float* __restrict__ W_prod_v,
  const float* __restrict__ W_lin_s, const float* __restrict__ W_lin_v,
  const float* __restrict__ W_read, float* __restrict__ out_node, float* __restrict__ out_feats)
{
  __shared__ float shA[4][4][64];
  __shared__ float shS[4][4][64];
  __shared__ float shP[4][4][64];
  int wave = threadIdx.x >> 6, lane = threadIdx.x & 63;
  int n = blockIdx.x*4 + wave;
  int o = n*64 + lane;
  shA[wave][0][lane] = agg_s[o]      * (1.f/16.f);
  shA[wave][1][lane] = agg_v[o]      * (1.f/16.f);
  shA[wave][2][lane] = agg_v[NF+o]   * (1.f/16.f);
  shA[wave][3][lane] = agg_v[2*NF+o] * (1.f/16.f);
  float4 nf = *(const float4*)(node_feats + (size_t)o*4);
  shS[wave][0][lane]=nf.x; shS[wave][1][lane]=nf.y; shS[wave][2][lane]=nf.z; shS[wave][3][lane]=nf.w;
  __syncthreads();
  int spec = specie[n];
  const float* Ws_ = Wrst + spec*4096;
  const float* Wv_ = Wrvt + spec*4096;
  float a_s=0.f,a0=0.f,a1=0.f,a2=0.f, r_s=0.f,r0=0.f,r1=0.f,r2=0.f;
  #pragma unroll 4
  for(int f=0; f<64; ++f){
    float wos=W_out_s[f*64+lane], wov=W_out_v[f*64+lane];
    a_s += shA[wave][0][f]*wos;
    a0  += shA[wave][1][f]*wov;
    a1  += shA[wave][2][f]*wov;
    a2  += shA[wave][3][f]*wov;
    float wrs=Ws_[f*64+lane], wrv=Wv_[f*64+lane];
    r_s += shS[wave][0][f]*wrs;
    r0  += shS[wave][1][f]*wrv;
    r1  += shS[wave][2][f]*wrv;
    r2  += shS[wave][3][f]*wrv;
  }
  a_s*=0.125f; a0*=0.125f; a1*=0.125f; a2*=0.125f;
  r_s*=0.125f; r0*=0.125f; r1*=0.125f; r2*=0.125f;
  float vv = a0*a0 + a1*a1 + a2*a2;
  float as2 = a_s*a_s;
  const float* Wp = W_prod_s + spec*320;
  float p_s = Wp[lane]*a_s + Wp[64+lane]*as2 + Wp[128+lane]*as2*a_s
            + Wp[192+lane]*vv + Wp[256+lane]*a_s*vv;
  const float* Wq = W_prod_v + spec*256;
  float coef = Wq[lane] + Wq[64+lane]*a_s + Wq[128+lane]*as2 + Wq[192+lane]*vv;
  shP[wave][0][lane] = p_s;
  shP[wave][1][lane] = coef*a0;
  shP[wave][2][lane] = coef*a1;
  shP[wave][3][lane] = coef*a2;
  __syncthreads();
  float fs=0.f,f0=0.f,f1=0.f,f2=0.f;
  #pragma unroll 4
  for(int f=0; f<64; ++f){
    float wls=W_lin_s[f*64+lane], wlv=W_lin_v[f*64+lane];
    fs += shP[wave][0][f]*wls;
    f0 += shP[wave][1][f]*wlv;
    f1 += shP[wave][2][f]*wlv;
    f2 += shP[wave][3][f]*wlv;
  }
  fs = fs*0.125f + r_s;
  f0 = f0*0.125f + r0;
  f1 = f1*0.125f + r1;
  f2 = f2*0.125f + r2;
  // node_out = (f_s @ W_read)/8
  float x = fs * W_read[lane];
  #pragma unroll
  for(int off=32; off; off>>=1) x += __shfl_down(x, off);
  if(lane==0) out_node[n] = x*0.125f;
  float4 o4; o4.x=fs; o4.y=f0; o4.z=f1; o4.w=f2;
  *(float4*)(out_feats + (size_t)o*4) = o4;
}

extern "C" void kernel_launch(void* const* d_in, const int* in_sizes, int n_in,
                              void* d_out, int out_size, void* d_ws, size_t ws_size,
                              hipStream_t stream) {
  const float* vectors    = (const float*)d_in[0];
  const float* node_feats = (const float*)d_in[1];
  const int*   node_specie= (const int*)  d_in[2];
  const float* radial     = (const float*)d_in[3];
  const int*   senders    = (const int*)  d_in[4];
  const int*   receivers  = (const int*)  d_in[5];
  const float* W_res_s    = (const float*)d_in[6];
  const float* W_res_v    = (const float*)d_in[7];
  const float* W_in_s     = (const float*)d_in[8];
  const float* W_in_v     = (const float*)d_in[9];
  const float* mlp_w1     = (const float*)d_in[10];
  const float* mlp_w2     = (const float*)d_in[11];
  const float* W_out_s    = (const float*)d_in[12];
  const float* W_out_v    = (const float*)d_in[13];
  const float* W_prod_s   = (const float*)d_in[14];
  const float* W_prod_v   = (const float*)d_in[15];
  const float* W_lin_s    = (const float*)d_in[16];
  const float* W_lin_v    = (const float*)d_in[17];
  const float* W_read     = (const float*)d_in[18];

  float* ws   = (float*)d_ws;
  float* h_s  = ws;                 // NF
  float* h_v  = ws + NF;            // 3*NF
  float* agg_s= ws + 4*(size_t)NF;  // NF
  float* agg_v= ws + 5*(size_t)NF;  // 3*NF
  float* Wrst = ws + 8*(size_t)NF;        // 40960
  float* Wrvt = ws + 8*(size_t)NF + 40960;

  hipMemsetAsync(agg_s, 0, (size_t)4*NF*sizeof(float), stream);
  k_transpose_res<<<160, 256, 0, stream>>>(W_res_s, W_res_v, Wrst, Wrvt);
  k_node_pre<<<NN/4, 256, 0, stream>>>(node_feats, W_in_s, W_in_v, h_s, h_v);
  k_edge<<<NE/(4*TB), 256, 0, stream>>>(vectors, radial, senders, receivers,
                                        mlp_w1, mlp_w2, h_s, h_v, agg_s, agg_v);
  k_node_post<<<NN/4, 256, 0, stream>>>(node_feats, node_specie, agg_s, agg_v,
                                        Wrst, Wrvt, W_out_s, W_out_v,
                                        W_prod_s, W_prod_v, W_lin_s, W_lin_v,
                                        W_read, (float*)d_out, (float*)d_out + NN);
}